// Round 1
// baseline (367.939 us; speedup 1.0000x reference)
//
#include <hip/hip_runtime.h>

#define IMH 512
#define IMW 512

// ---------------------------------------------------------------------------
// Fused LOI kernel, v2: shared-iso dataflow.
//
// Old version: each thread privately evaluated a 7x14 iso (RBF) neighborhood
// -> 5.9x redundant exp/VALU per block (25088 evals vs 4256 distinct), plus
// 24 scalar stride-32B stores/thread. New dataflow (per block = one
// combo x 32x8 tile):
//
//   A: clipped image tile -> separable 9+9 sigma smooth  sm[14][38]
//      (rows ty0-3..+10, cols tx0-3..+34)                       [as before]
//   B: iso[14][38][8] in LDS, computed ONCE: RBF(sm) * norm, with the
//      reference's zero-pad semantics folded in as a validity mask
//      (iso == 0 outside the image). n innermost.
//   C: vertical 7-tap alpha conv for ALL 3 alphas sharing the same 7 iso
//      reads -> vv[3][8][38][8] in LDS.
//   D: horizontal 7-tap in registers, float4 (4 n) accumulators, float4
//      stores. Wave-level store pattern = contiguous 1KB (col,ng lanes).
//
// LDS phase overlap: smem[12112] floats:
//   [0,560)      sm (both phases)
//   [560,1616)   imt   / phase2: iso [560,4816)
//   [1616,2288)  svt
//   [4816,12112) vv
// Total 48.4KB -> 3 blocks/CU. All LDS b128 traffic is lane-contiguous
// (conflict-free); iso layout [rr][jj][n] makes (jj,ng)-lane reads 1KB
// contiguous.
// ---------------------------------------------------------------------------
#define SM_OFF   0
#define IMT_OFF  560
#define SVT_OFF  1616
#define ISO_OFF  560
#define VV_OFF   4816

__global__ __launch_bounds__(256) void loi_fused(
    const float* __restrict__ im,      // [512][512][3]
    const float* __restrict__ sigk,    // [2][9][9]
    const float* __restrict__ alphak,  // [3][7][7]
    const float* __restrict__ binc,    // [8]
    const float* __restrict__ betas,   // [2]
    float* __restrict__ out)           // [36][512][512][8]
{
  const int t     = threadIdx.x;
  const int combo = blockIdx.z;        // b*6 + s*3 + c
  const int b     = combo / 6;
  const int sc    = combo % 6;
  const int s     = sc / 3;
  const int c     = sc % 3;
  const int tx0   = blockIdx.x * 32;
  const int ty0   = blockIdx.y * 8;

  __shared__ __align__(16) float smem[12112];
  __shared__ float kf[3][8];    // alpha 1D factors (row sums of 2D kernels)
  __shared__ float sf[12];      // sigma 1D factors (9 used)

  float* imt = smem + IMT_OFF;  // 22 x 48 (46 cols used)
  float* svt = smem + SVT_OFF;  // 14 x 48
  float* smt = smem + SM_OFF;   // 14 x 40 (38 cols used)

  // --- A1: stage clipped image tile (zero outside image) ---
  for (int e = t; e < 1056; e += 256) {
    int j = e / 48, i = e - j * 48;
    float v = 0.f;
    if (i < 46) {
      int gy = ty0 + j - 7, gx = tx0 + i - 7;
      if (gy >= 0 && gy < IMH && gx >= 0 && gx < IMW) {
        v = im[(gy * IMW + gx) * 3 + c];
        v = fminf(fmaxf(v, 0.f), 1.f);           // clip(im, 0, 1)
      }
    }
    imt[e] = v;
  }
  // 1D separable factors (row sums of the 2D kernels; Gaussians are exact
  // outer products so rowsum[i]*rowsum[j] == k2d[i][j]).
  if (t < 9) {
    float acc = 0.f;
    #pragma unroll
    for (int j = 0; j < 9; j++) acc += sigk[s * 81 + t * 9 + j];
    sf[t] = acc;
  }
  if (t >= 32 && t < 56) {
    int a = (t - 32) >> 3, d = t & 7;
    float v = 0.f;
    if (d < 7) {
      #pragma unroll
      for (int j = 0; j < 7; j++) v += alphak[a * 49 + d * 7 + j];
    }
    kf[a][d] = v;
  }
  __syncthreads();

  // --- A2: vertical 9-tap sigma smooth: rows 0..13 (smooth ty0-3..+10) ---
  for (int e = t; e < 672; e += 256) {
    int rr = e / 48, i = e - rr * 48;
    if (i < 46) {
      float acc = 0.f;
      #pragma unroll
      for (int d = 0; d < 9; d++) acc = fmaf(sf[d], imt[(rr + d) * 48 + i], acc);
      svt[e] = acc;
    }
  }
  __syncthreads();

  // --- A3: horizontal 9-tap: smooth cols 0..37 (tx0-3..tx0+34) ---
  for (int e = t; e < 560; e += 256) {
    int rr = e / 40, j = e - rr * 40;
    if (j < 38) {
      float acc = 0.f;
      #pragma unroll
      for (int d = 0; d < 9; d++) acc = fmaf(sf[d], svt[rr * 48 + j + d], acc);
      smt[e] = acc;
    }
  }
  __syncthreads();

  // --- B: iso[14][38][8] = valid * exp2(c2*(sm-ctr)^2) * norm  (ONCE) ---
  // flat idx e = (rr*38 + jj)*8 + n; n = e&7 == t&7 (256 % 8 == 0).
  const float beta = betas[b];
  const float norm = 0.39894228040143268f / beta;      // 1/(sqrt(2pi)*beta)
  const float c2   = -0.72134752044448170f / (beta * beta); // -0.5*log2e/b^2
  const float ctr  = binc[t & 7];
  float* iso = smem + ISO_OFF;
  for (int e = t; e < 4256; e += 256) {
    int q  = e >> 3;
    int rr = q / 38, jj = q - rr * 38;
    float v  = smt[rr * 40 + jj];
    float tt = v - ctr;
    float E  = exp2f(tt * tt * c2) * norm;
    int X = tx0 + jj - 3, Y = ty0 + rr - 3;   // iso coords (ref zero-pads iso)
    bool valid = ((unsigned)X < IMW) && ((unsigned)Y < IMH);
    iso[e] = valid ? E : 0.f;
  }
  __syncthreads();

  // hoist alpha factors to registers (used by C and D)
  float k0[7], k1[7], k2[7];
  #pragma unroll
  for (int d = 0; d < 7; d++) {
    k0[d] = kf[0][d];
    k1[d] = kf[1][d];
    k2[d] = kf[2][d];
  }

  // --- C: vertical 7-tap for all 3 alphas -> vv[3][8][38][8] ---
  // 7 iso reads shared across the 3 alphas. Lane->(jj,ng) contiguous.
  float* vv = smem + VV_OFF;
  for (int g = t; g < 608; g += 256) {     // 8 rows * 38 cols * 2 ngroups
    int ng = g & 1;
    int h  = g >> 1;
    int yr = h / 38, jj = h - yr * 38;
    int base = yr * 304 + jj * 8 + ng * 4;
    float a0x = 0.f, a0y = 0.f, a0z = 0.f, a0w = 0.f;
    float a1x = 0.f, a1y = 0.f, a1z = 0.f, a1w = 0.f;
    float a2x = 0.f, a2y = 0.f, a2z = 0.f, a2w = 0.f;
    #pragma unroll
    for (int d = 0; d < 7; d++) {
      float4 w = *(const float4*)&iso[base + d * 304];
      a0x = fmaf(k0[d], w.x, a0x); a0y = fmaf(k0[d], w.y, a0y);
      a0z = fmaf(k0[d], w.z, a0z); a0w = fmaf(k0[d], w.w, a0w);
      a1x = fmaf(k1[d], w.x, a1x); a1y = fmaf(k1[d], w.y, a1y);
      a1z = fmaf(k1[d], w.z, a1z); a1w = fmaf(k1[d], w.w, a1w);
      a2x = fmaf(k2[d], w.x, a2x); a2y = fmaf(k2[d], w.y, a2y);
      a2z = fmaf(k2[d], w.z, a2z); a2w = fmaf(k2[d], w.w, a2w);
    }
    *(float4*)&vv[base]        = make_float4(a0x, a0y, a0z, a0w);
    *(float4*)&vv[base + 2432] = make_float4(a1x, a1y, a1z, a1w);
    *(float4*)&vv[base + 4864] = make_float4(a2x, a2y, a2z, a2w);
  }
  __syncthreads();

  // --- D: horizontal 7-tap in registers, float4 stores ---
  // thread -> col = t&31, ng = bit5, rg = t>>6 (2 rows each).
  // Wave store pattern: (col,ng) lanes -> contiguous 1KB per instr.
  {
    const int col = t & 31;
    const int ng  = (t >> 5) & 1;
    const int rg  = t >> 6;
    const int gx  = tx0 + col;
    const float* vb = vv + col * 8 + ng * 4;
    #pragma unroll
    for (int rowi = 0; rowi < 2; rowi++) {
      const int row = rg * 2 + rowi;
      const float* vr = vb + row * 304;
      const size_t pb = (((size_t)(ty0 + row) * 512 + gx) << 3) + ng * 4;
      float* op = out + ((size_t)combo << 21) + pb;   // plane a*12+combo
      // alpha 0
      {
        float ax = 0.f, ay = 0.f, az = 0.f, aw = 0.f;
        #pragma unroll
        for (int d = 0; d < 7; d++) {
          float4 w = *(const float4*)(vr + d * 8);
          ax = fmaf(k0[d], w.x, ax); ay = fmaf(k0[d], w.y, ay);
          az = fmaf(k0[d], w.z, az); aw = fmaf(k0[d], w.w, aw);
        }
        *(float4*)op = make_float4(ax, ay, az, aw);
      }
      // alpha 1
      {
        float ax = 0.f, ay = 0.f, az = 0.f, aw = 0.f;
        #pragma unroll
        for (int d = 0; d < 7; d++) {
          float4 w = *(const float4*)(vr + 2432 + d * 8);
          ax = fmaf(k1[d], w.x, ax); ay = fmaf(k1[d], w.y, ay);
          az = fmaf(k1[d], w.z, az); aw = fmaf(k1[d], w.w, aw);
        }
        *(float4*)(op + ((size_t)12 << 21)) = make_float4(ax, ay, az, aw);
      }
      // alpha 2
      {
        float ax = 0.f, ay = 0.f, az = 0.f, aw = 0.f;
        #pragma unroll
        for (int d = 0; d < 7; d++) {
          float4 w = *(const float4*)(vr + 4864 + d * 8);
          ax = fmaf(k2[d], w.x, ax); ay = fmaf(k2[d], w.y, ay);
          az = fmaf(k2[d], w.z, az); aw = fmaf(k2[d], w.w, aw);
        }
        *(float4*)(op + ((size_t)24 << 21)) = make_float4(ax, ay, az, aw);
      }
    }
  }
}

extern "C" void kernel_launch(void* const* d_in, const int* in_sizes, int n_in,
                              void* d_out, int out_size, void* d_ws, size_t ws_size,
                              hipStream_t stream)
{
  const float* im   = (const float*)d_in[0];   // (512,512,3)
  const float* sigk = (const float*)d_in[1];   // (2,9,9)
  const float* alpk = (const float*)d_in[2];   // (3,7,7)
  const float* binc = (const float*)d_in[3];   // (8,)
  const float* bets = (const float*)d_in[4];   // (2,)
  float* out = (float*)d_out;                  // (3,2,2,3,512,512,8)

  loi_fused<<<dim3(16, 64, 12), 256, 0, stream>>>(im, sigk, alpk, binc, bets, out);
}

// Round 2
// 324.799 us; speedup vs baseline: 1.1328x; 1.1328x over previous
//
#include <hip/hip_runtime.h>
#include <hip/hip_fp16.h>

#define IMH 512
#define IMW 512

// ---------------------------------------------------------------------------
// Fused LOI kernel, v3: fp16 iso/vv dataflow.
//
// v2 profile theory: LDS data port + 3-blocks/CU occupancy bound the kernel.
// v3 stores the two intermediate tensors (iso, vv) in fp16 with n packed
// innermost so every conv-tap read is ONE ds_read_b128 carrying all 8 bins:
//   iso[14][38][8] half (8.5 KB)   vv[3][8][38][8] half (14.6 KB)
// Total LDS ~25.5 KB -> 6 blocks/CU (was 48.4 KB -> 3). Conv math uses
// packed __hfma2 (half the FMA issue). All LDS b128 traffic is lane-
// contiguous 16B-stride (conflict-free). Error budget: iso<=20, fp16 rel
// 4.9e-4, two 7-tap accums -> ~0.02-0.04 abs worst case (tol 0.125).
//
// Phases (5 barriers):
//   A1 image tile clip+stage (f32)  A2 vertical 9-tap  A3 horizontal 9-tap
//   B  iso = valid * norm * exp2(c2*(sm-ctr)^2)  -> half2 writes
//   C  vertical 7-tap x3 alphas, hfma2, 7 b128 reads/point -> vv
//   D  horizontal 7-tap x3 alphas, 21 b128 reads/thread, f32 finish+store
//
// LDS union: [imt 22x48 | svt 14x48] (phase A) overlaid by [iso | vv]
// (phases B-D); smt[14][40] f32 lives separately (read by B only).
// ---------------------------------------------------------------------------

__device__ __forceinline__ __half2 bc_h2(int v) {
  union { int i; __half2 h; } u; u.i = v; return u.h;
}
__device__ __forceinline__ int bc_i(__half2 v) {
  union { int i; __half2 h; } u; u.h = v; return u.i;
}

__global__ __launch_bounds__(256, 6) void loi_fused(
    const float* __restrict__ im,      // [512][512][3]
    const float* __restrict__ sigk,    // [2][9][9]
    const float* __restrict__ alphak,  // [3][7][7]
    const float* __restrict__ binc,    // [8]
    const float* __restrict__ betas,   // [2]
    float* __restrict__ out)           // [36][512][512][8]
{
  const int t     = threadIdx.x;
  const int combo = blockIdx.z;        // b*6 + s*3 + c
  const int b     = combo / 6;
  const int sc    = combo % 6;
  const int s     = sc / 3;
  const int c     = sc % 3;
  const int tx0   = blockIdx.x * 32;
  const int ty0   = blockIdx.y * 8;

  __shared__ __align__(16) float smt[560];            // [14][40], 38 cols used
  __shared__ __align__(16) unsigned char uni[23104];  // phase A | phases B-D
  __shared__ float kf[3][8];                          // alpha 1D factors
  __shared__ float sf[12];                            // sigma 1D factors

  float*  imt = (float*)uni;             // [22][48] (46 cols used)
  float*  svt = (float*)(uni + 4224);    // [14][48]
  __half* iso = (__half*)uni;            // [14][38][8]
  __half* vv  = (__half*)(uni + 8512);   // [3][8][38][8]

  // --- A1: stage clipped image tile (zero outside image) ---
  for (int e = t; e < 1056; e += 256) {
    int j = e / 48, i = e - j * 48;
    float v = 0.f;
    if (i < 46) {
      int gy = ty0 + j - 7, gx = tx0 + i - 7;
      if (gy >= 0 && gy < IMH && gx >= 0 && gx < IMW) {
        v = im[(gy * IMW + gx) * 3 + c];
        v = fminf(fmaxf(v, 0.f), 1.f);
      }
    }
    imt[e] = v;
  }
  // 1D separable factors (row sums; Gaussian kernels are exact outer products)
  if (t < 9) {
    float acc = 0.f;
    #pragma unroll
    for (int j = 0; j < 9; j++) acc += sigk[s * 81 + t * 9 + j];
    sf[t] = acc;
  }
  if (t >= 32 && t < 56) {
    int a = (t - 32) >> 3, d = t & 7;
    float v = 0.f;
    if (d < 7) {
      #pragma unroll
      for (int j = 0; j < 7; j++) v += alphak[a * 49 + d * 7 + j];
    }
    kf[a][d] = v;
  }
  __syncthreads();

  // --- A2: vertical 9-tap sigma smooth (rows 0..13 = smooth ty0-3..+10) ---
  for (int e = t; e < 672; e += 256) {
    int rr = e / 48, i = e - rr * 48;
    if (i < 46) {
      float acc = 0.f;
      #pragma unroll
      for (int d = 0; d < 9; d++) acc = fmaf(sf[d], imt[(rr + d) * 48 + i], acc);
      svt[e] = acc;
    }
  }
  __syncthreads();

  // --- A3: horizontal 9-tap -> smt (cols 0..37 = tx0-3..tx0+34) ---
  for (int e = t; e < 560; e += 256) {
    int rr = e / 40, j = e - rr * 40;
    if (j < 38) {
      float acc = 0.f;
      #pragma unroll
      for (int d = 0; d < 9; d++) acc = fmaf(sf[d], svt[rr * 48 + j + d], acc);
      smt[e] = acc;
    }
  }
  __syncthreads();

  // --- B: iso (half2 per 2 bins), zero-pad semantics folded in ---
  const float beta = betas[b];
  const float norm = 0.39894228040143268f / beta;           // 1/(sqrt(2pi)*b)
  const float c2   = -0.72134752044448170f / (beta * beta); // -0.5*log2e/b^2
  const int   np   = t & 3;               // bin pair id (u & 3 == t & 3)
  const float ctr0 = binc[2 * np];
  const float ctr1 = binc[2 * np + 1];
  for (int u = t; u < 2128; u += 256) {   // 14*38*4 half2 units
    int q  = u >> 2;                      // rr*38 + jj
    int rr = q / 38, jj = q - rr * 38;
    float v  = smt[rr * 40 + jj];
    float t0 = v - ctr0, t1 = v - ctr1;
    float E0 = exp2f(t0 * t0 * c2) * norm;
    float E1 = exp2f(t1 * t1 * c2) * norm;
    int X = tx0 + jj - 3, Y = ty0 + rr - 3;  // iso coords (ref zero-pads iso)
    if (!(((unsigned)X < IMW) && ((unsigned)Y < IMH))) { E0 = 0.f; E1 = 0.f; }
    *(__half2*)(iso + q * 8 + np * 2) = __floats2half2_rn(E0, E1);
  }
  __syncthreads();

  // alpha 1D factors as packed half2 (used by C and D)
  __half2 kh[3][7];
  #pragma unroll
  for (int a = 0; a < 3; a++)
    #pragma unroll
    for (int d = 0; d < 7; d++) kh[a][d] = __float2half2_rn(kf[a][d]);

  // --- C: vertical 7-tap x3 alphas; 7 shared b128 reads per point ---
  for (int g = t; g < 304; g += 256) {    // 8 rows * 38 cols
    int yr = g / 38, jj = g - yr * 38;
    const int base = yr * 38 + jj;        // iso point index
    __half2 acc[3][4];
    #pragma unroll
    for (int a = 0; a < 3; a++)
      #pragma unroll
      for (int q = 0; q < 4; q++) acc[a][q] = __floats2half2_rn(0.f, 0.f);
    #pragma unroll
    for (int d = 0; d < 7; d++) {
      int4 raw = *(const int4*)(iso + ((base + d * 38) << 3));
      __half2 w0 = bc_h2(raw.x), w1 = bc_h2(raw.y);
      __half2 w2 = bc_h2(raw.z), w3 = bc_h2(raw.w);
      #pragma unroll
      for (int a = 0; a < 3; a++) {
        acc[a][0] = __hfma2(kh[a][d], w0, acc[a][0]);
        acc[a][1] = __hfma2(kh[a][d], w1, acc[a][1]);
        acc[a][2] = __hfma2(kh[a][d], w2, acc[a][2]);
        acc[a][3] = __hfma2(kh[a][d], w3, acc[a][3]);
      }
    }
    #pragma unroll
    for (int a = 0; a < 3; a++) {
      int4 o;
      o.x = bc_i(acc[a][0]); o.y = bc_i(acc[a][1]);
      o.z = bc_i(acc[a][2]); o.w = bc_i(acc[a][3]);
      *(int4*)(vv + ((((a << 3) + yr) * 38 + jj) << 3)) = o;
    }
  }
  __syncthreads();

  // --- D: horizontal 7-tap x3 alphas; split fp16 chains, f32 finish ---
  const int col = t & 31;
  const int row = t >> 5;
  float* op = out + ((size_t)combo << 21)
                  + ((size_t)(ty0 + row) * 512 + (tx0 + col)) * 8;
  #pragma unroll
  for (int a = 0; a < 3; a++) {
    const int base = ((a << 3) + row) * 38 + col;
    __half2 pA0, pA1, pA2, pA3, pB0, pB1, pB2, pB3;
    {  // d = 0 / d = 1 initialize the two chains
      int4 r0 = *(const int4*)(vv + (base << 3));
      pA0 = __hmul2(kh[a][0], bc_h2(r0.x)); pA1 = __hmul2(kh[a][0], bc_h2(r0.y));
      pA2 = __hmul2(kh[a][0], bc_h2(r0.z)); pA3 = __hmul2(kh[a][0], bc_h2(r0.w));
      int4 r1 = *(const int4*)(vv + ((base + 1) << 3));
      pB0 = __hmul2(kh[a][1], bc_h2(r1.x)); pB1 = __hmul2(kh[a][1], bc_h2(r1.y));
      pB2 = __hmul2(kh[a][1], bc_h2(r1.z)); pB3 = __hmul2(kh[a][1], bc_h2(r1.w));
    }
    #pragma unroll
    for (int d = 2; d < 7; d += 2) {
      int4 rA = *(const int4*)(vv + ((base + d) << 3));
      pA0 = __hfma2(kh[a][d], bc_h2(rA.x), pA0);
      pA1 = __hfma2(kh[a][d], bc_h2(rA.y), pA1);
      pA2 = __hfma2(kh[a][d], bc_h2(rA.z), pA2);
      pA3 = __hfma2(kh[a][d], bc_h2(rA.w), pA3);
      if (d + 1 < 7) {
        int4 rB = *(const int4*)(vv + ((base + d + 1) << 3));
        pB0 = __hfma2(kh[a][d + 1], bc_h2(rB.x), pB0);
        pB1 = __hfma2(kh[a][d + 1], bc_h2(rB.y), pB1);
        pB2 = __hfma2(kh[a][d + 1], bc_h2(rB.z), pB2);
        pB3 = __hfma2(kh[a][d + 1], bc_h2(rB.w), pB3);
      }
    }
    float2 a0 = __half22float2(pA0), b0 = __half22float2(pB0);
    float2 a1 = __half22float2(pA1), b1 = __half22float2(pB1);
    float2 a2 = __half22float2(pA2), b2 = __half22float2(pB2);
    float2 a3 = __half22float2(pA3), b3 = __half22float2(pB3);
    float4 lo = make_float4(a0.x + b0.x, a0.y + b0.y, a1.x + b1.x, a1.y + b1.y);
    float4 hi = make_float4(a2.x + b2.x, a2.y + b2.y, a3.x + b3.x, a3.y + b3.y);
    float* p = op + ((size_t)(a * 12) << 21);
    *(float4*)p       = lo;
    *(float4*)(p + 4) = hi;
  }
}

extern "C" void kernel_launch(void* const* d_in, const int* in_sizes, int n_in,
                              void* d_out, int out_size, void* d_ws, size_t ws_size,
                              hipStream_t stream)
{
  const float* im   = (const float*)d_in[0];   // (512,512,3)
  const float* sigk = (const float*)d_in[1];   // (2,9,9)
  const float* alpk = (const float*)d_in[2];   // (3,7,7)
  const float* binc = (const float*)d_in[3];   // (8,)
  const float* bets = (const float*)d_in[4];   // (2,)
  float* out = (float*)d_out;                  // (3,2,2,3,512,512,8)

  loi_fused<<<dim3(16, 64, 12), 256, 0, stream>>>(im, sigk, alpk, binc, bets, out);
}